// Round 3
// baseline (1482.919 us; speedup 1.0000x reference)
//
#include <hip/hip_runtime.h>
#include <hip/hip_bf16.h>

typedef __attribute__((ext_vector_type(8))) short short8;
typedef __attribute__((ext_vector_type(4))) float floatx4;

#define DD 256
#define PPB 32            // parents owned per gemm1 block
#define FSTRIDE 264       // padded f32 row stride of LDS fc accumulator (264&31=8 -> banks spread)

__device__ __forceinline__ unsigned short f2bf(float f) {
    unsigned int u = __builtin_bit_cast(unsigned int, f);
    u += 0x7FFFu + ((u >> 16) & 1u);   // round-to-nearest-even
    return (unsigned short)(u >> 16);
}

__device__ __forceinline__ float sigm(float x) { return 1.0f / (1.0f + __expf(-x)); }
__device__ __forceinline__ float tanh_fast(float x) { return 2.0f / (1.0f + __expf(-2.0f * x)) - 1.0f; }

__device__ __forceinline__ short8 pack8(float4 a, float4 b) {
    short8 r;
    r[0] = (short)f2bf(a.x); r[1] = (short)f2bf(a.y);
    r[2] = (short)f2bf(a.z); r[3] = (short)f2bf(a.w);
    r[4] = (short)f2bf(b.x); r[5] = (short)f2bf(b.y);
    r[6] = (short)f2bf(b.z); r[7] = (short)f2bf(b.w);
    return r;
}

// async global->LDS, 16B per lane; LDS dest = uniform base + lane*16 (linear, conflict-free);
// fragment layout achieved by permuting the per-lane GLOBAL source address (m173 pattern)
__device__ __forceinline__ void stage16(const unsigned short* g, unsigned short* l) {
    __builtin_amdgcn_global_load_lds(
        (const __attribute__((address_space(1))) unsigned int*)g,
        (__attribute__((address_space(3))) unsigned int*)l, 16, 0, 0);
}

// ---------------- pack weights to bf16, transposed [N][K] ----------------
__global__ void pack_weights(const float* __restrict__ W_f, const float* __restrict__ W_g,
                             unsigned short* __restrict__ WfT, unsigned short* __restrict__ WgT) {
    int idx = blockIdx.x * 256 + threadIdx.x;
    if (idx < 65536) {
        int n = idx >> 8, k = idx & 255;
        WfT[idx] = f2bf(W_f[k * 256 + n]);          // WfT[n][k]
    } else {
        int i2 = idx - 65536;                        // 0..196607
        int n = i2 >> 8, k = i2 & 255;
        WgT[i2] = f2bf(W_g[k * 768 + n]);            // WgT[n][k], n<768
    }
}

// ---------------- CSR offsets from sorted segment_ids ----------------
__global__ void build_start(const int* __restrict__ seg, int E, int P, int* __restrict__ start) {
    int e = blockIdx.x * blockDim.x + threadIdx.x;
    if (e >= E) return;
    int s = seg[e];
    if (e == 0) {
        for (int p = 0; p <= s; ++p) start[p] = 0;
    } else {
        int sp = seg[e - 1];
        for (int p = sp + 1; p <= s; ++p) start[p] = e;
    }
    if (e == E - 1) {
        for (int p = s + 1; p <= P; ++p) start[p] = E;
    }
}

// ---------------- hs_sum: one wave per parent, zero atomics, 4 loads in flight ----------------
__global__ void hs_reduce(const float* __restrict__ child_hs, const int* __restrict__ start,
                          int P, float* __restrict__ hs_sum) {
    int wave = threadIdx.x >> 6, lane = threadIdx.x & 63;
    int p = blockIdx.x * 4 + wave;
    if (p >= P) return;
    int lo = start[p], hi = start[p + 1];
    float4 acc = make_float4(0.f, 0.f, 0.f, 0.f);
    const float4* src = (const float4*)child_hs;
    int e = lo;
    for (; e + 4 <= hi; e += 4) {
        float4 v0 = src[(size_t)(e + 0) * 64 + lane];
        float4 v1 = src[(size_t)(e + 1) * 64 + lane];
        float4 v2 = src[(size_t)(e + 2) * 64 + lane];
        float4 v3 = src[(size_t)(e + 3) * 64 + lane];
        acc.x += v0.x + v1.x + v2.x + v3.x;
        acc.y += v0.y + v1.y + v2.y + v3.y;
        acc.z += v0.z + v1.z + v2.z + v3.z;
        acc.w += v0.w + v1.w + v2.w + v3.w;
    }
    for (; e < hi; ++e) {
        float4 v = src[(size_t)e * 64 + lane];
        acc.x += v.x; acc.y += v.y; acc.z += v.z; acc.w += v.w;
    }
    ((float4*)hs_sum)[(size_t)p * 64 + lane] = acc;
}

// ---------------- GEMM1: fc[p] = sum_{children e of p} sigmoid(hs[e]@W_f + b_f) * cs[e] -------
// Parent-owned blocks: block b owns parents [b*32, b*32+32); their children are the contiguous
// sorted range [start[p0], start[p0+32]) (avg 128 rows). Children processed in 64-row MFMA
// chunks (4 waves x 16 rows, N=256, K=256); F*cs is run-combined then accumulated into a padded
// LDS fc accumulator with ds_add_f32 (NO global atomics), written back once, coalesced.
__global__ __launch_bounds__(256, 2) void gemm1_fc(
    const float* __restrict__ child_hs, const float* __restrict__ child_cs,
    const int* __restrict__ seg, const int* __restrict__ start,
    const unsigned short* __restrict__ WfT, const float* __restrict__ b_f,
    float* __restrict__ fc, int E, int P) {
    __shared__ __align__(16) unsigned short ldsB[8192];        // 16 KB: one 32x256 bf16 k-slice
    __shared__ __align__(16) float fcacc[PPB * FSTRIDE];       // 33 KB padded accumulator
    const int tid = threadIdx.x;
    const int w = tid >> 6, lane = tid & 63;
    const int nl = lane & 15, q = lane >> 4;
    const int p0 = blockIdx.x * PPB;
    const int lo = start[p0], hi = start[p0 + PPB];

    // zero the accumulator (first k-step barrier fences this)
    for (int i = tid; i < PPB * FSTRIDE / 4; i += 256)
        ((float4*)fcacc)[i] = make_float4(0.f, 0.f, 0.f, 0.f);

    // staging source for slot (tile = w*4+r, q, nl): WfT + (tile*16+nl)*256 + q*8 + ks*32
    const unsigned short* Wsrc = WfT + ((w * 64 + nl) << 8) + q * 8;

    for (int cb = lo; cb < hi; cb += 64) {
        floatx4 acc[16];
#pragma unroll
        for (int t = 0; t < 16; ++t) acc[t] = (floatx4){0.f, 0.f, 0.f, 0.f};

        int erow = cb + w * 16 + nl;
        const float* Arow = child_hs + (size_t)(erow < E ? erow : E - 1) * DD + q * 8;

        for (int ks = 0; ks < 8; ++ks) {
            __syncthreads();   // prev k-step reads done / fcacc zero done / prev epilogue done
#pragma unroll
            for (int r = 0; r < 4; ++r)
                stage16(Wsrc + ks * 32 + (r << 12), &ldsB[(w * 4 + r) << 9]);
            float4 a0 = *(const float4*)(Arow + ks * 32);
            float4 a1 = *(const float4*)(Arow + ks * 32 + 4);
            short8 af = pack8(a0, a1);
            __syncthreads();   // stage complete (barrier drains vmcnt)
#pragma unroll
            for (int t = 0; t < 16; ++t) {
                short8 bf = ((const short8*)ldsB)[t * 64 + lane];
                acc[t] = __builtin_amdgcn_mfma_f32_16x16x32_bf16(af, bf, acc[t], 0, 0, 0);
            }
        }

        // chunk epilogue: C/D layout col = lane&15 (tile-local), row = q*4 + reg
        int e0 = cb + w * 16 + q * 4;
        int sr[4];
#pragma unroll
        for (int r = 0; r < 4; ++r) {
            int e = e0 + r;
            sr[r] = (e < hi) ? (seg[e] - p0) : -1;     // valid rows: s in [0,32)
        }
#pragma unroll
        for (int t = 0; t < 16; ++t) {
            int n = t * 16 + nl;
            float bias = b_f[n];
            float vr[4];
#pragma unroll
            for (int r = 0; r < 4; ++r) {
                float cs = (sr[r] >= 0) ? child_cs[(size_t)(e0 + r) * DD + n] : 0.f;
                vr[r] = sigm(acc[t][r] + bias) * cs;
            }
            // run-combine consecutive equal segments (sorted) -> fewer LDS atomics
            float a = vr[0]; int s = sr[0];
#pragma unroll
            for (int r = 1; r < 4; ++r) {
                if (sr[r] == s) { a += vr[r]; }
                else {
                    if (s >= 0) atomicAdd(&fcacc[s * FSTRIDE + n], a);
                    a = vr[r]; s = sr[r];
                }
            }
            if (s >= 0) atomicAdd(&fcacc[s * FSTRIDE + n], a);
        }
    }

    __syncthreads();
    // write fc for owned parents: 32 rows x 64 float4, coalesced, exactly once (no memset needed)
    for (int i = tid; i < PPB * 64; i += 256) {
        int row = i >> 6, c4 = i & 63;
        float4 v = *(const float4*)&fcacc[row * FSTRIDE + c4 * 4];
        ((float4*)fc)[(((size_t)(p0 + row)) << 6) + c4] = v;
    }
}

// ---------------- GEMM2: gates = hs_sum @ W_gates + b; fused LSTM epilogue ----------------
// block = 512 thr = 8 waves in 2(row)x4(col) grid; M_block = 64 rows; N = 768; K = 256.
__global__ __launch_bounds__(512, 2) void gemm2_lstm(
    const float* __restrict__ hs_sum, const unsigned short* __restrict__ WgT,
    const float* __restrict__ b_g, float* __restrict__ h_out, float* __restrict__ c_out, int P) {
    __shared__ __align__(16) unsigned short ldsB[24576];   // 48 KB: 768x32 bf16 k-slice
    const int tid = threadIdx.x;
    const int w = tid >> 6, lane = tid & 63;
    const int wr = w >> 2, wc = w & 3;                 // wave row (0..1), wave col (0..3)
    const int nl = lane & 15, q = lane >> 4;
    const int p_base = blockIdx.x * 64;

    floatx4 acc[2][12];
#pragma unroll
    for (int rt = 0; rt < 2; ++rt)
#pragma unroll
        for (int t = 0; t < 12; ++t) acc[rt][t] = (floatx4){0.f, 0.f, 0.f, 0.f};

    const float* Arow0 = hs_sum + (size_t)(p_base + wr * 32 + nl) * DD + q * 8;
    const float* Arow1 = Arow0 + (size_t)16 * DD;
    // staging source for slot (tile = w*6+r, q, nl)
    const unsigned short* Wsrc = WgT + ((w * 96 + nl) << 8) + q * 8;

    // prologue: stage ks=0
#pragma unroll
    for (int r = 0; r < 6; ++r)
        stage16(Wsrc + (r << 12), &ldsB[(w * 6 + r) << 9]);

    for (int ks = 0; ks < 8; ++ks) {
        // A loads overlap with the stage still in flight
        float4 a0 = *(const float4*)(Arow0 + ks * 32);
        float4 a1 = *(const float4*)(Arow0 + ks * 32 + 4);
        float4 a2 = *(const float4*)(Arow1 + ks * 32);
        float4 a3 = *(const float4*)(Arow1 + ks * 32 + 4);
        short8 af0 = pack8(a0, a1);
        short8 af1 = pack8(a2, a3);
        __syncthreads();   // stage(ks) complete
#pragma unroll
        for (int cgl = 0; cgl < 4; ++cgl) {
#pragma unroll
            for (int part = 0; part < 3; ++part) {
                int t = part * 16 + (wc * 4 + cgl);    // global col-tile in [0,48)
                short8 bf = ((const short8*)ldsB)[t * 64 + lane];
                acc[0][cgl * 3 + part] =
                    __builtin_amdgcn_mfma_f32_16x16x32_bf16(af0, bf, acc[0][cgl * 3 + part], 0, 0, 0);
                acc[1][cgl * 3 + part] =
                    __builtin_amdgcn_mfma_f32_16x16x32_bf16(af1, bf, acc[1][cgl * 3 + part], 0, 0, 0);
            }
        }
        __syncthreads();   // all reads done (also fences A reads before epilogue overwrites hs_sum)
        if (ks < 7) {
            const unsigned short* ws = Wsrc + (ks + 1) * 32;
#pragma unroll
            for (int r = 0; r < 6; ++r)
                stage16(ws + (r << 12), &ldsB[(w * 6 + r) << 9]);
        }
    }

    // epilogue: C/D layout col = lane&15 (within tile), row = q*4 + reg
#pragma unroll
    for (int rt = 0; rt < 2; ++rt) {
#pragma unroll
        for (int cgl = 0; cgl < 4; ++cgl) {
            int n = (wc * 4 + cgl) * 16 + nl;
            float bi = b_g[n], bo = b_g[256 + n], bg = b_g[512 + n];
#pragma unroll
            for (int reg = 0; reg < 4; ++reg) {
                int p = p_base + wr * 32 + rt * 16 + q * 4 + reg;
                if (p < P) {
                    float I = acc[rt][cgl * 3 + 0][reg] + bi;
                    float O = acc[rt][cgl * 3 + 1][reg] + bo;
                    float G = acc[rt][cgl * 3 + 2][reg] + bg;
                    float iv = sigm(I), ov = sigm(O), gv = tanh_fast(G);
                    float c = iv * gv + c_out[(size_t)p * DD + n];   // c_out currently holds fc
                    float hv = ov * tanh_fast(c);
                    h_out[(size_t)p * DD + n] = hv;
                    c_out[(size_t)p * DD + n] = c;
                }
            }
        }
    }
}

extern "C" void kernel_launch(void* const* d_in, const int* in_sizes, int n_in,
                              void* d_out, int out_size, void* d_ws, size_t ws_size,
                              hipStream_t stream) {
    const float* child_hs = (const float*)d_in[0];
    const float* child_cs = (const float*)d_in[1];
    const int*   seg      = (const int*)d_in[2];
    // d_in[3] = num_segments (device scalar) — P derived from out_size instead
    const float* W_gates  = (const float*)d_in[4];
    const float* b_gates  = (const float*)d_in[5];
    const float* W_f      = (const float*)d_in[6];
    const float* b_f      = (const float*)d_in[7];

    const int D = 256;
    const int E = in_sizes[0] / D;
    const int P = out_size / (2 * D);

    float* h_out = (float*)d_out;                         // doubles as hs_sum accumulator
    float* c_out = (float*)d_out + (size_t)P * D;         // doubles as fc accumulator

    unsigned short* WfT = (unsigned short*)d_ws;          // 65536 bf16
    unsigned short* WgT = WfT + 65536;                    // 196608 bf16
    int* start = (int*)(WgT + 196608);                    // P+1 ints

    pack_weights<<<1024, 256, 0, stream>>>(W_f, W_gates, WfT, WgT);
    build_start<<<(E + 255) / 256, 256, 0, stream>>>(seg, E, P, start);
    hs_reduce<<<(P + 3) / 4, 256, 0, stream>>>(child_hs, start, P, h_out);
    gemm1_fc<<<P / PPB, 256, 0, stream>>>(child_hs, child_cs, seg, start, WfT, b_f, c_out, E, P);
    gemm2_lstm<<<(P + 63) / 64, 512, 0, stream>>>(h_out, WgT, b_gates, h_out, c_out, P);
}

// Round 4
// 1397.084 us; speedup vs baseline: 1.0614x; 1.0614x over previous
//
#include <hip/hip_runtime.h>
#include <hip/hip_bf16.h>

typedef __attribute__((ext_vector_type(8))) short short8;
typedef __attribute__((ext_vector_type(4))) short sh4;
typedef __attribute__((ext_vector_type(4))) float floatx4;

#define DD 256
#define PPB 32            // parents owned per block (P % 32 == 0)
#define FSTRIDE 264       // f32 row stride of LDS fc accumulator (pad spreads banks)
#define HSTRIDE 264       // bf16 row stride of LDS hs_sum (264*2B = 528B = 33*16B -> conflict-light)

__device__ __forceinline__ unsigned short f2bf(float f) {
    unsigned int u = __builtin_bit_cast(unsigned int, f);
    u += 0x7FFFu + ((u >> 16) & 1u);   // round-to-nearest-even
    return (unsigned short)(u >> 16);
}

__device__ __forceinline__ float sigm(float x) { return 1.0f / (1.0f + __expf(-x)); }
__device__ __forceinline__ float tanh_fast(float x) { return 2.0f / (1.0f + __expf(-2.0f * x)) - 1.0f; }

__device__ __forceinline__ short8 pack8(float4 a, float4 b) {
    short8 r;
    r[0] = (short)f2bf(a.x); r[1] = (short)f2bf(a.y);
    r[2] = (short)f2bf(a.z); r[3] = (short)f2bf(a.w);
    r[4] = (short)f2bf(b.x); r[5] = (short)f2bf(b.y);
    r[6] = (short)f2bf(b.z); r[7] = (short)f2bf(b.w);
    return r;
}

// async global->LDS, 16B per lane; LDS dest = uniform base + lane*16 (linear, conflict-free);
// fragment layout achieved by permuting the per-lane GLOBAL source address (m173 pattern)
__device__ __forceinline__ void stage16(const unsigned short* g, unsigned short* l) {
    __builtin_amdgcn_global_load_lds(
        (const __attribute__((address_space(1))) unsigned int*)g,
        (__attribute__((address_space(3))) unsigned int*)l, 16, 0, 0);
}

// ---------------- pack weights to bf16, transposed [N][K] ----------------
__global__ void pack_weights(const float* __restrict__ W_f, const float* __restrict__ W_g,
                             unsigned short* __restrict__ WfT, unsigned short* __restrict__ WgT) {
    int idx = blockIdx.x * 256 + threadIdx.x;
    if (idx < 65536) {
        int n = idx >> 8, k = idx & 255;
        WfT[idx] = f2bf(W_f[k * 256 + n]);          // WfT[n][k]
    } else {
        int i2 = idx - 65536;                        // 0..196607
        int n = i2 >> 8, k = i2 & 255;
        WgT[i2] = f2bf(W_g[k * 768 + n]);            // WgT[n][k], n<768
    }
}

// ---------------- CSR offsets from sorted segment_ids ----------------
__global__ void build_start(const int* __restrict__ seg, int E, int P, int* __restrict__ start) {
    int e = blockIdx.x * blockDim.x + threadIdx.x;
    if (e >= E) return;
    int s = seg[e];
    if (e == 0) {
        for (int p = 0; p <= s; ++p) start[p] = 0;
    } else {
        int sp = seg[e - 1];
        for (int p = sp + 1; p <= s; ++p) start[p] = e;
    }
    if (e == E - 1) {
        for (int p = s + 1; p <= P; ++p) start[p] = E;
    }
}

// ---------------- FUSED: hs_reduce + GEMM1(fc) + GEMM2(gates) + LSTM epilogue ----------------
// Block owns parents [p0, p0+32); children = contiguous sorted range [start[p0], start[p0+32]).
// Phase 1.5: wave-per-parent hs_sum -> hsacc (bf16, LDS). Phase 1: F=sigmoid(hs@Wf+b), fc into
// fcacc via LDS atomics, 128-row superchunks (Wf k-slice staged once for both 64-row halves).
// Phase 2: gates = hsacc @ Wg (A from LDS, Wg staged 16KB/part), LSTM epilogue, write h/c once.
__global__ __launch_bounds__(256, 2) void fused(
    const float* __restrict__ child_hs, const float* __restrict__ child_cs,
    const int* __restrict__ seg, const int* __restrict__ start,
    const unsigned short* __restrict__ WfT, const unsigned short* __restrict__ WgT,
    const float* __restrict__ b_f, const float* __restrict__ b_g,
    float* __restrict__ h_out, float* __restrict__ c_out, int E) {
    __shared__ __align__(16) unsigned short ldsB[8192];        // 16 KB staged k-slice
    __shared__ __align__(16) float fcacc[PPB * FSTRIDE];       // 33 KB fc accumulator
    __shared__ __align__(16) unsigned short hsacc[PPB * HSTRIDE];  // 16.5 KB hs_sum (bf16)
    const int tid = threadIdx.x;
    const int w = tid >> 6, lane = tid & 63;
    const int nl = lane & 15, q = lane >> 4;
    const int p0 = blockIdx.x * PPB;
    const int lo = start[p0], hi = start[p0 + PPB];

    // zero fc accumulator (fenced from other threads' atomics by first barrier below)
    for (int i = tid; i < PPB * FSTRIDE / 4; i += 256)
        ((float4*)fcacc)[i] = make_float4(0.f, 0.f, 0.f, 0.f);

    // ---- phase 1.5: per-parent hs_sum (wave per parent, 8 parents/wave); also prefetches
    // the block's child rows into L1/L2 for phase 1's A loads ----
    for (int j = 0; j < 8; ++j) {
        int ppl = w * 8 + j;
        int lp = start[p0 + ppl], hp = start[p0 + ppl + 1];
        float4 a = make_float4(0.f, 0.f, 0.f, 0.f);
        const float4* src = (const float4*)child_hs;
        for (int e = lp; e < hp; ++e) {
            float4 v = src[(size_t)e * 64 + lane];
            a.x += v.x; a.y += v.y; a.z += v.z; a.w += v.w;
        }
        sh4 s4;
        s4[0] = (short)f2bf(a.x); s4[1] = (short)f2bf(a.y);
        s4[2] = (short)f2bf(a.z); s4[3] = (short)f2bf(a.w);
        *(sh4*)&hsacc[ppl * HSTRIDE + lane * 4] = s4;   // row ppl, cols lane*4..+3
    }

    // ---- phase 1: fc over children in 128-row superchunks ----
    const unsigned short* WfS = WfT + ((w * 64 + nl) << 8) + q * 8;

    // epilogue for one 64-row chunk of F: run-combine sorted segments -> LDS atomics
    auto fc_epi = [&](const floatx4 (&acc)[16], int ebase) {
        int e0 = ebase + w * 16 + q * 4;
        int sr[4];
#pragma unroll
        for (int r = 0; r < 4; ++r) {
            int e = e0 + r;
            sr[r] = (e < hi) ? (seg[e] - p0) : -1;
        }
#pragma unroll
        for (int t = 0; t < 16; ++t) {
            int n = t * 16 + nl;
            float bias = b_f[n];
            float vr[4];
#pragma unroll
            for (int r = 0; r < 4; ++r) {
                float cs = (sr[r] >= 0) ? child_cs[(size_t)(e0 + r) * DD + n] : 0.f;
                vr[r] = sigm(acc[t][r] + bias) * cs;
            }
            float a = vr[0]; int s = sr[0];
#pragma unroll
            for (int r = 1; r < 4; ++r) {
                if (sr[r] == s) { a += vr[r]; }
                else {
                    if (s >= 0) atomicAdd(&fcacc[s * FSTRIDE + n], a);
                    a = vr[r]; s = sr[r];
                }
            }
            if (s >= 0) atomicAdd(&fcacc[s * FSTRIDE + n], a);
        }
    };

    for (int cb = lo; cb < hi; cb += 128) {
        const bool two = (cb + 64) < hi;
        floatx4 acc0[16], acc1[16];
#pragma unroll
        for (int t = 0; t < 16; ++t) {
            acc0[t] = (floatx4){0.f, 0.f, 0.f, 0.f};
            acc1[t] = (floatx4){0.f, 0.f, 0.f, 0.f};
        }
        int er0 = cb + w * 16 + nl, er1 = er0 + 64;
        const float* A0 = child_hs + (size_t)(er0 < E ? er0 : E - 1) * DD + q * 8;
        const float* A1 = child_hs + (size_t)(er1 < E ? er1 : E - 1) * DD + q * 8;

        for (int ks = 0; ks < 8; ++ks) {
            __syncthreads();   // prev k-step LDS reads done / fcacc zeroing fenced
#pragma unroll
            for (int r = 0; r < 4; ++r)
                stage16(WfS + ks * 32 + (r << 12), &ldsB[(w * 4 + r) << 9]);
            float4 a0 = *(const float4*)(A0 + ks * 32);
            float4 a1 = *(const float4*)(A0 + ks * 32 + 4);
            short8 af0 = pack8(a0, a1);
            float4 b0 = *(const float4*)(A1 + ks * 32);
            float4 b1 = *(const float4*)(A1 + ks * 32 + 4);
            short8 af1 = pack8(b0, b1);
            __syncthreads();   // stage complete (barrier drains vmcnt)
            if (two) {
#pragma unroll
                for (int t = 0; t < 16; ++t) {
                    short8 bf = ((const short8*)ldsB)[t * 64 + lane];
                    acc0[t] = __builtin_amdgcn_mfma_f32_16x16x32_bf16(af0, bf, acc0[t], 0, 0, 0);
                    acc1[t] = __builtin_amdgcn_mfma_f32_16x16x32_bf16(af1, bf, acc1[t], 0, 0, 0);
                }
            } else {
#pragma unroll
                for (int t = 0; t < 16; ++t) {
                    short8 bf = ((const short8*)ldsB)[t * 64 + lane];
                    acc0[t] = __builtin_amdgcn_mfma_f32_16x16x32_bf16(af0, bf, acc0[t], 0, 0, 0);
                }
            }
        }
        fc_epi(acc0, cb);
        if (two) fc_epi(acc1, cb + 64);
    }

    // ---- phase 2: gates = hs_sum @ W_gates for the 32 owned parents ----
    __syncthreads();   // hsacc writes + all fcacc atomics visible; also covers hi==lo case

    floatx4 gacc[2][12];
#pragma unroll
    for (int rt = 0; rt < 2; ++rt)
#pragma unroll
        for (int t = 0; t < 12; ++t) gacc[rt][t] = (floatx4){0.f, 0.f, 0.f, 0.f};

    const unsigned short* WgS = WgT + ((w * 64 + nl) << 8) + q * 8;

    for (int ks = 0; ks < 8; ++ks) {
        // A fragments straight from LDS hs accumulator (already bf16)
        short8 af0 = *(const short8*)&hsacc[nl * HSTRIDE + ks * 32 + q * 8];
        short8 af1 = *(const short8*)&hsacc[(16 + nl) * HSTRIDE + ks * 32 + q * 8];
#pragma unroll
        for (int part = 0; part < 3; ++part) {
            __syncthreads();   // previous ldsB readers done
#pragma unroll
            for (int r = 0; r < 4; ++r)
                stage16(WgS + part * 65536 + ks * 32 + (r << 12), &ldsB[(w * 4 + r) << 9]);
            __syncthreads();   // stage complete
#pragma unroll
            for (int cgl = 0; cgl < 4; ++cgl) {
                short8 bf = ((const short8*)ldsB)[(w * 4 + cgl) * 64 + lane];
                gacc[0][cgl * 3 + part] =
                    __builtin_amdgcn_mfma_f32_16x16x32_bf16(af0, bf, gacc[0][cgl * 3 + part], 0, 0, 0);
                gacc[1][cgl * 3 + part] =
                    __builtin_amdgcn_mfma_f32_16x16x32_bf16(af1, bf, gacc[1][cgl * 3 + part], 0, 0, 0);
            }
        }
    }

    // ---- LSTM epilogue: c = i*g + fc, h = o*tanh(c); single coalesced global write ----
#pragma unroll
    for (int cgl = 0; cgl < 4; ++cgl) {
        int n = (w * 4 + cgl) * 16 + nl;
        float bi = b_g[n], bo = b_g[256 + n], bg = b_g[512 + n];
#pragma unroll
        for (int rt = 0; rt < 2; ++rt) {
#pragma unroll
            for (int reg = 0; reg < 4; ++reg) {
                int pl = rt * 16 + q * 4 + reg;
                float I = gacc[rt][cgl * 3 + 0][reg] + bi;
                float O = gacc[rt][cgl * 3 + 1][reg] + bo;
                float G = gacc[rt][cgl * 3 + 2][reg] + bg;
                float iv = sigm(I), ov = sigm(O), gv = tanh_fast(G);
                float c = iv * gv + fcacc[pl * FSTRIDE + n];
                float hv = ov * tanh_fast(c);
                size_t p = (size_t)(p0 + pl);
                h_out[p * DD + n] = hv;
                c_out[p * DD + n] = c;
            }
        }
    }
}

extern "C" void kernel_launch(void* const* d_in, const int* in_sizes, int n_in,
                              void* d_out, int out_size, void* d_ws, size_t ws_size,
                              hipStream_t stream) {
    const float* child_hs = (const float*)d_in[0];
    const float* child_cs = (const float*)d_in[1];
    const int*   seg      = (const int*)d_in[2];
    // d_in[3] = num_segments (device scalar) — P derived from out_size instead
    const float* W_gates  = (const float*)d_in[4];
    const float* b_gates  = (const float*)d_in[5];
    const float* W_f      = (const float*)d_in[6];
    const float* b_f      = (const float*)d_in[7];

    const int D = 256;
    const int E = in_sizes[0] / D;
    const int P = out_size / (2 * D);

    float* h_out = (float*)d_out;
    float* c_out = (float*)d_out + (size_t)P * D;

    unsigned short* WfT = (unsigned short*)d_ws;          // 65536 bf16
    unsigned short* WgT = WfT + 65536;                    // 196608 bf16
    int* start = (int*)(WgT + 196608);                    // P+1 ints

    pack_weights<<<1024, 256, 0, stream>>>(W_f, W_gates, WfT, WgT);
    build_start<<<(E + 255) / 256, 256, 0, stream>>>(seg, E, P, start);
    fused<<<P / PPB, 256, 0, stream>>>(child_hs, child_cs, seg, start, WfT, WgT,
                                       b_f, b_gates, h_out, c_out, E);
}